// Round 1
// baseline (295.429 us; speedup 1.0000x reference)
//
#include <hip/hip_runtime.h>

// DetectionLoss: B=32768 batches, grid G=7, A=2 anchors, C=3 classes, M=20 targets.
// Strategy: one block = 16 batches. Build per-batch cell->last-valid-target table
// in LDS (last-write-wins matches numpy scatter semantics), then stream the
// 16*98 cells (2x float4 coalesced loads), accumulate 4 loss sums + num_pos,
// block-reduce, atomicAdd to d_ws. Finalize kernel combines and divides.

namespace {
constexpr int kG = 7;
constexpr int kA = 2;
constexpr int kM = 20;
constexpr int kCells = kG * kG * kA;   // 98
constexpr int kCh = 8;                  // 5 + C
constexpr int kNB = 16;                 // batches per block
constexpr int kBlock = 256;
}

__device__ __forceinline__ float softplusf(float x) {
    // logaddexp(x, 0) = max(x,0) + log1p(exp(-|x|))  (matches jax.nn.softplus)
    return fmaxf(x, 0.0f) + log1pf(expf(-fabsf(x)));
}

__global__ __launch_bounds__(kBlock) void det_loss_main(
    const float* __restrict__ preds,
    const float* __restrict__ tboxes,
    const int* __restrict__ tlabels,
    const int* __restrict__ nobjs,
    const float* __restrict__ anchors,
    const float* __restrict__ cweights,
    float* __restrict__ accum,   // [5]: obj, noobj, bbox, cls, npos
    int B)
{
    __shared__ float4 s_tv[kNB * kM];      // per-target (tx,ty,tw,th)
    __shared__ int    s_lab[kNB * kM];     // per-target label
    __shared__ short  s_cell[kNB * kM];    // per-target cell idx (-1 invalid)
    __shared__ short  s_table[kNB * kCells]; // cell -> target flat idx (-1 none)
    __shared__ int    s_nobj[kNB];
    __shared__ float  s_red[kBlock / 64][5];

    const int tid = threadIdx.x;
    const int b0 = blockIdx.x * kNB;

    // uniform constants (L1/scalar-cached)
    const float a00 = anchors[0], a01 = anchors[1];
    const float a10 = anchors[2], a11 = anchors[3];
    const float cw0 = cweights[0], cw1 = cweights[1], cw2 = cweights[2];

    if (tid < kNB) {
        const int b = b0 + tid;
        s_nobj[tid] = (b < B) ? nobjs[b] : 0;
    }
    for (int k = tid; k < kNB * kCells; k += kBlock) s_table[k] = -1;
    __syncthreads();

    // ---- Phase 1: per-target assignment values ----
    for (int j = tid; j < kNB * kM; j += kBlock) {
        const int bl = j / kM;
        const int m  = j - bl * kM;
        const int b  = b0 + bl;
        short cell = -1;
        float4 tv = make_float4(0.f, 0.f, 0.f, 0.f);
        int lab = 0;
        if (b < B) {
            const float4 box = ((const float4*)tboxes)[(size_t)b0 * kM + j];
            const float x1 = box.x, y1 = box.y, x2 = box.z, y2 = box.w;
            const float cx = (x1 + x2) * 0.5f, cy = (y1 + y2) * 0.5f;
            const float w = x2 - x1, h = y2 - y1;
            if (w > 0.f && h > 0.f && m < s_nobj[bl]) {
                const int gi = min(max((int)floorf(cy * (float)kG), 0), kG - 1);
                const int gj = min(max((int)floorf(cx * (float)kG), 0), kG - 1);
                const float wg = w * (float)kG, hg = h * (float)kG;
                const float i0 = fminf(wg, a00) * fminf(hg, a01);
                const float u0 = wg * hg + a00 * a01 - i0;
                const float r0 = i0 / (u0 + 1e-6f);
                const float i1 = fminf(wg, a10) * fminf(hg, a11);
                const float u1 = wg * hg + a10 * a11 - i1;
                const float r1 = i1 / (u1 + 1e-6f);
                const int a = (r1 > r0) ? 1 : 0;   // argmax, first-max wins
                const float aw = a ? a10 : a00;
                const float ah = a ? a11 : a01;
                tv.x = cx * (float)kG - (float)gj;
                tv.y = cy * (float)kG - (float)gi;
                tv.z = logf(fmaxf(wg, 0.01f) / (aw + 1e-6f));
                tv.w = logf(fmaxf(hg, 0.01f) / (ah + 1e-6f));
                cell = (short)((gi * kG + gj) * kA + a);
                lab = tlabels[(size_t)b0 * kM + j];
            }
        }
        s_tv[j] = tv;
        s_lab[j] = lab;
        s_cell[j] = cell;
    }
    __syncthreads();

    // ---- Phase 1b: serial per-batch fill => last-write-wins dedup ----
    if (tid < kNB) {
        const int base = tid * kM;
        for (int m = 0; m < kM; ++m) {
            const short c = s_cell[base + m];
            if (c >= 0) s_table[tid * kCells + c] = (short)(base + m);
        }
    }
    __syncthreads();

    // ---- Phase 2: stream cells, accumulate losses ----
    float acc_obj = 0.f, acc_noobj = 0.f, acc_bbox = 0.f, acc_cls = 0.f;
    int npos = 0;
    const float4* __restrict__ p4 = (const float4*)preds;
    const long long cellbase = (long long)b0 * kCells;
    for (int i = tid; i < kNB * kCells; i += kBlock) {
        const int bl = i / kCells;
        if (b0 + bl >= B) break;
        const long long ci = (cellbase + i) * 2;
        const float4 p0 = p4[ci];
        const float4 p1 = p4[ci + 1];
        const float po = p0.x;
        const short j = s_table[i];
        if (j >= 0) {
            acc_obj += softplusf(-po);
            const float4 tv = s_tv[j];
            const float d0 = p0.y - tv.x;
            const float d1 = p0.z - tv.y;
            const float d2 = p0.w - tv.z;
            const float d3 = p1.x - tv.w;
            float ad;
            ad = fabsf(d0); acc_bbox += (ad < 1.f) ? 0.5f * d0 * d0 : ad - 0.5f;
            ad = fabsf(d1); acc_bbox += (ad < 1.f) ? 0.5f * d1 * d1 : ad - 0.5f;
            ad = fabsf(d2); acc_bbox += (ad < 1.f) ? 0.5f * d2 * d2 : ad - 0.5f;
            ad = fabsf(d3); acc_bbox += (ad < 1.f) ? 0.5f * d3 * d3 : ad - 0.5f;
            const int lab = s_lab[j];
            const float c0 = p1.y, c1 = p1.z, c2 = p1.w;
            const float mx = fmaxf(c0, fmaxf(c1, c2));
            const float lse = mx + logf(expf(c0 - mx) + expf(c1 - mx) + expf(c2 - mx));
            const float logit = (lab == 0) ? c0 : ((lab == 1) ? c1 : c2);
            const float cwv   = (lab == 0) ? cw0 : ((lab == 1) ? cw1 : cw2);
            acc_cls += cwv * (lse - logit);
            ++npos;
        } else {
            acc_noobj += softplusf(po);
        }
    }

    // ---- Reduce: wave shuffle -> LDS -> one atomicAdd x5 per block ----
    float vals[5] = {acc_obj, acc_noobj, acc_bbox, acc_cls, (float)npos};
    #pragma unroll
    for (int k = 0; k < 5; ++k) {
        float v = vals[k];
        #pragma unroll
        for (int off = 32; off > 0; off >>= 1) v += __shfl_down(v, off, 64);
        vals[k] = v;
    }
    const int wave = tid >> 6;
    const int lane = tid & 63;
    if (lane == 0) {
        #pragma unroll
        for (int k = 0; k < 5; ++k) s_red[wave][k] = vals[k];
    }
    __syncthreads();
    if (tid == 0) {
        #pragma unroll
        for (int k = 0; k < 5; ++k) {
            float t = 0.f;
            #pragma unroll
            for (int w = 0; w < kBlock / 64; ++w) t += s_red[w][k];
            atomicAdd(&accum[k], t);
        }
    }
}

__global__ void det_loss_final(const float* __restrict__ accum,
                               float* __restrict__ out)
{
    const float npv = fmaxf(accum[4], 1.0f);
    out[0] = (5.0f * accum[2] + 1.0f * accum[0] + 0.5f * accum[1]
              + 2.0f * accum[3]) / npv;
}

extern "C" void kernel_launch(void* const* d_in, const int* in_sizes, int n_in,
                              void* d_out, int out_size, void* d_ws, size_t ws_size,
                              hipStream_t stream) {
    const float* preds    = (const float*)d_in[0];
    const float* tboxes   = (const float*)d_in[1];
    const int*   tlabels  = (const int*)d_in[2];
    const int*   nobjs    = (const int*)d_in[3];
    const float* anchors  = (const float*)d_in[4];
    const float* cweights = (const float*)d_in[5];
    float* out = (float*)d_out;
    float* accum = (float*)d_ws;

    const int B = in_sizes[0] / (kCells * kCh);   // /784

    // d_ws is re-poisoned 0xAA before every call: zero the accumulators.
    hipMemsetAsync(accum, 0, 5 * sizeof(float), stream);

    const int blocks = (B + kNB - 1) / kNB;
    det_loss_main<<<blocks, kBlock, 0, stream>>>(
        preds, tboxes, tlabels, nobjs, anchors, cweights, accum, B);
    det_loss_final<<<1, 1, 0, stream>>>(accum, out);
}

// Round 2
// 179.912 us; speedup vs baseline: 1.6421x; 1.6421x over previous
//
#include <hip/hip_runtime.h>

// DetectionLoss: B=32768 batches, grid G=7, A=2 anchors, C=3 classes, M=20 targets.
// One block = 16 batches. Per-batch cell->last-valid-target table in LDS
// (last-write-wins = numpy scatter semantics), stream 16*98 cells with 2x
// float4 coalesced loads, accumulate 4 loss sums + num_pos, block-reduce.
// R2: NO atomics — per-block partials plain-stored SoA to d_ws, tiny reduce
// kernel finishes. (R1 post-mortem: 5 same-line atomicAdds x 2048 blocks
// serialized in LLC -> 169us kernel with VALUBusy 20%; atomics removed.)

namespace {
constexpr int kG = 7;
constexpr int kA = 2;
constexpr int kM = 20;
constexpr int kCells = kG * kG * kA;   // 98
constexpr int kCh = 8;                  // 5 + C
constexpr int kNB = 16;                 // batches per block
constexpr int kBlock = 256;
}

__device__ __forceinline__ float softplusf(float x) {
    // logaddexp(x, 0) = max(x,0) + log1p(exp(-|x|))  (matches jax.nn.softplus)
    return fmaxf(x, 0.0f) + log1pf(expf(-fabsf(x)));
}

__global__ __launch_bounds__(kBlock) void det_loss_main(
    const float* __restrict__ preds,
    const float* __restrict__ tboxes,
    const int* __restrict__ tlabels,
    const int* __restrict__ nobjs,
    const float* __restrict__ anchors,
    const float* __restrict__ cweights,
    float* __restrict__ partial,   // SoA [5][gridDim.x]: obj, noobj, bbox, cls, npos
    int B)
{
    __shared__ float4 s_tv[kNB * kM];      // per-target (tx,ty,tw,th)
    __shared__ int    s_lab[kNB * kM];     // per-target label
    __shared__ short  s_cell[kNB * kM];    // per-target cell idx (-1 invalid)
    __shared__ short  s_table[kNB * kCells]; // cell -> target flat idx (-1 none)
    __shared__ int    s_nobj[kNB];
    __shared__ float  s_red[kBlock / 64][5];

    const int tid = threadIdx.x;
    const int b0 = blockIdx.x * kNB;

    const float a00 = anchors[0], a01 = anchors[1];
    const float a10 = anchors[2], a11 = anchors[3];
    const float cw0 = cweights[0], cw1 = cweights[1], cw2 = cweights[2];

    if (tid < kNB) {
        const int b = b0 + tid;
        s_nobj[tid] = (b < B) ? nobjs[b] : 0;
    }
    for (int k = tid; k < kNB * kCells; k += kBlock) s_table[k] = -1;
    __syncthreads();

    // ---- Phase 1: per-target assignment values ----
    for (int j = tid; j < kNB * kM; j += kBlock) {
        const int bl = j / kM;
        const int m  = j - bl * kM;
        const int b  = b0 + bl;
        short cell = -1;
        float4 tv = make_float4(0.f, 0.f, 0.f, 0.f);
        int lab = 0;
        if (b < B) {
            const float4 box = ((const float4*)tboxes)[(size_t)b0 * kM + j];
            const float x1 = box.x, y1 = box.y, x2 = box.z, y2 = box.w;
            const float cx = (x1 + x2) * 0.5f, cy = (y1 + y2) * 0.5f;
            const float w = x2 - x1, h = y2 - y1;
            if (w > 0.f && h > 0.f && m < s_nobj[bl]) {
                const int gi = min(max((int)floorf(cy * (float)kG), 0), kG - 1);
                const int gj = min(max((int)floorf(cx * (float)kG), 0), kG - 1);
                const float wg = w * (float)kG, hg = h * (float)kG;
                const float i0 = fminf(wg, a00) * fminf(hg, a01);
                const float u0 = wg * hg + a00 * a01 - i0;
                const float r0 = i0 / (u0 + 1e-6f);
                const float i1 = fminf(wg, a10) * fminf(hg, a11);
                const float u1 = wg * hg + a10 * a11 - i1;
                const float r1 = i1 / (u1 + 1e-6f);
                const int a = (r1 > r0) ? 1 : 0;   // argmax, first-max wins
                const float aw = a ? a10 : a00;
                const float ah = a ? a11 : a01;
                tv.x = cx * (float)kG - (float)gj;
                tv.y = cy * (float)kG - (float)gi;
                tv.z = logf(fmaxf(wg, 0.01f) / (aw + 1e-6f));
                tv.w = logf(fmaxf(hg, 0.01f) / (ah + 1e-6f));
                cell = (short)((gi * kG + gj) * kA + a);
                lab = tlabels[(size_t)b0 * kM + j];
            }
        }
        s_tv[j] = tv;
        s_lab[j] = lab;
        s_cell[j] = cell;
    }
    __syncthreads();

    // ---- Phase 1b: serial per-batch fill => last-write-wins dedup ----
    if (tid < kNB) {
        const int base = tid * kM;
        for (int m = 0; m < kM; ++m) {
            const short c = s_cell[base + m];
            if (c >= 0) s_table[tid * kCells + c] = (short)(base + m);
        }
    }
    __syncthreads();

    // ---- Phase 2: stream cells, accumulate losses ----
    float acc_obj = 0.f, acc_noobj = 0.f, acc_bbox = 0.f, acc_cls = 0.f;
    int npos = 0;
    const float4* __restrict__ p4 = (const float4*)preds;
    const long long cellbase = (long long)b0 * kCells;
    for (int i = tid; i < kNB * kCells; i += kBlock) {
        const int bl = i / kCells;
        if (b0 + bl >= B) break;
        const long long ci = (cellbase + i) * 2;
        const float4 p0 = p4[ci];
        const float4 p1 = p4[ci + 1];
        const float po = p0.x;
        const short j = s_table[i];
        if (j >= 0) {
            acc_obj += softplusf(-po);
            const float4 tv = s_tv[j];
            const float d0 = p0.y - tv.x;
            const float d1 = p0.z - tv.y;
            const float d2 = p0.w - tv.z;
            const float d3 = p1.x - tv.w;
            float ad;
            ad = fabsf(d0); acc_bbox += (ad < 1.f) ? 0.5f * d0 * d0 : ad - 0.5f;
            ad = fabsf(d1); acc_bbox += (ad < 1.f) ? 0.5f * d1 * d1 : ad - 0.5f;
            ad = fabsf(d2); acc_bbox += (ad < 1.f) ? 0.5f * d2 * d2 : ad - 0.5f;
            ad = fabsf(d3); acc_bbox += (ad < 1.f) ? 0.5f * d3 * d3 : ad - 0.5f;
            const int lab = s_lab[j];
            const float c0 = p1.y, c1 = p1.z, c2 = p1.w;
            const float mx = fmaxf(c0, fmaxf(c1, c2));
            const float lse = mx + logf(expf(c0 - mx) + expf(c1 - mx) + expf(c2 - mx));
            const float logit = (lab == 0) ? c0 : ((lab == 1) ? c1 : c2);
            const float cwv   = (lab == 0) ? cw0 : ((lab == 1) ? cw1 : cw2);
            acc_cls += cwv * (lse - logit);
            ++npos;
        } else {
            acc_noobj += softplusf(po);
        }
    }

    // ---- Reduce: wave shuffle -> LDS -> 5 plain stores per block (no atomics) ----
    float vals[5] = {acc_obj, acc_noobj, acc_bbox, acc_cls, (float)npos};
    #pragma unroll
    for (int k = 0; k < 5; ++k) {
        float v = vals[k];
        #pragma unroll
        for (int off = 32; off > 0; off >>= 1) v += __shfl_down(v, off, 64);
        vals[k] = v;
    }
    const int wave = tid >> 6;
    const int lane = tid & 63;
    if (lane == 0) {
        #pragma unroll
        for (int k = 0; k < 5; ++k) s_red[wave][k] = vals[k];
    }
    __syncthreads();
    if (tid == 0) {
        const int nb = gridDim.x;
        #pragma unroll
        for (int k = 0; k < 5; ++k) {
            float t = 0.f;
            #pragma unroll
            for (int w = 0; w < kBlock / 64; ++w) t += s_red[w][k];
            partial[(size_t)k * nb + blockIdx.x] = t;
        }
    }
}

__global__ __launch_bounds__(kBlock) void det_loss_reduce(
    const float* __restrict__ partial, int nblocks, float* __restrict__ out)
{
    __shared__ float s_red[kBlock / 64][5];
    const int tid = threadIdx.x;
    float v[5] = {0.f, 0.f, 0.f, 0.f, 0.f};
    for (int i = tid; i < nblocks; i += kBlock) {
        #pragma unroll
        for (int k = 0; k < 5; ++k) v[k] += partial[(size_t)k * nblocks + i];
    }
    #pragma unroll
    for (int k = 0; k < 5; ++k) {
        float x = v[k];
        #pragma unroll
        for (int off = 32; off > 0; off >>= 1) x += __shfl_down(x, off, 64);
        v[k] = x;
    }
    const int wave = tid >> 6;
    const int lane = tid & 63;
    if (lane == 0) {
        #pragma unroll
        for (int k = 0; k < 5; ++k) s_red[wave][k] = v[k];
    }
    __syncthreads();
    if (tid == 0) {
        float t[5];
        #pragma unroll
        for (int k = 0; k < 5; ++k) {
            float s = 0.f;
            #pragma unroll
            for (int w = 0; w < kBlock / 64; ++w) s += s_red[w][k];
            t[k] = s;
        }
        const float npv = fmaxf(t[4], 1.0f);
        out[0] = (5.0f * t[2] + 1.0f * t[0] + 0.5f * t[1] + 2.0f * t[3]) / npv;
    }
}

extern "C" void kernel_launch(void* const* d_in, const int* in_sizes, int n_in,
                              void* d_out, int out_size, void* d_ws, size_t ws_size,
                              hipStream_t stream) {
    const float* preds    = (const float*)d_in[0];
    const float* tboxes   = (const float*)d_in[1];
    const int*   tlabels  = (const int*)d_in[2];
    const int*   nobjs    = (const int*)d_in[3];
    const float* anchors  = (const float*)d_in[4];
    const float* cweights = (const float*)d_in[5];
    float* out = (float*)d_out;
    float* partial = (float*)d_ws;   // [5][nblocks], fully overwritten every call

    const int B = in_sizes[0] / (kCells * kCh);   // /784
    const int blocks = (B + kNB - 1) / kNB;

    det_loss_main<<<blocks, kBlock, 0, stream>>>(
        preds, tboxes, tlabels, nobjs, anchors, cweights, partial, B);
    det_loss_reduce<<<1, kBlock, 0, stream>>>(partial, blocks, out);
}

// Round 3
// 178.123 us; speedup vs baseline: 1.6586x; 1.0100x over previous
//
#include <hip/hip_runtime.h>

// DetectionLoss: B=32768, G=7, A=2, C=3, M=20.
// R3 structure: block = 32 batches, 448 threads (7 waves).
//  - Phase 1: per-target cell assignment (tv, cell) into LDS.
//  - Phase 1b: parallel dedup (winner = valid && no LATER same-batch target in
//    same cell == numpy last-write-wins), LDS-compact winners into s_pos.
//  - Phase 2: branchless stream of ALL 3136 obj logits (4B strided loads,
//    exactly 7 per thread, fully unrolled) -> noobj sum.
//  - Phase 2b: ~300 compacted positives/block: gather 32B, obj/bbox/cls terms,
//    noobj correction (-sp(po)); sp(-x) = sp(x) - x.
//  - Block partials plain-stored SoA (no atomics, per R2), tiny reduce kernel.
// R2 post-mortem: main <60us but wave divergence made every wave run both the
// heavy positive path and noobj path; this version has zero divergent heavy code
// in the stream loop.

namespace {
constexpr int kG = 7;
constexpr int kA = 2;
constexpr int kM = 20;
constexpr int kCells = kG * kG * kA;     // 98
constexpr int kCh = 8;                   // 5 + C
constexpr int kNB = 32;                  // batches per block
constexpr int kBlock = 448;              // 7 waves; kNB*kCells/kBlock == 7 exactly
constexpr int kTgt = kNB * kM;           // 640
constexpr int kIters = (kNB * kCells) / kBlock;  // 7
}

__device__ __forceinline__ float softplus_fast(float x) {
    // logaddexp(x,0); fast exp/log — absmax threshold 0.557 leaves huge slack
    return fmaxf(x, 0.0f) + __logf(1.0f + __expf(-fabsf(x)));
}

__global__ __launch_bounds__(kBlock) void det_loss_main(
    const float* __restrict__ preds,
    const float* __restrict__ tboxes,
    const int* __restrict__ tlabels,
    const int* __restrict__ nobjs,
    const float* __restrict__ anchors,
    const float* __restrict__ cweights,
    float* __restrict__ partial,   // SoA [5][gridDim.x]: obj, noobj, bbox, cls, npos
    int B)
{
    __shared__ float4 s_tv[kTgt];        // per-target (tx,ty,tw,th)
    __shared__ short  s_cell[kTgt];      // block-local cell = bl*98+c, -1 invalid
    __shared__ int    s_pos[kTgt];       // compacted winners: (j<<16)|cell
    __shared__ int    s_nobj[kNB];
    __shared__ int    s_npos;
    __shared__ float  s_red[kBlock / 64][4];

    const int tid = threadIdx.x;
    const int b0 = blockIdx.x * kNB;

    if (tid < kNB) {
        const int b = b0 + tid;
        s_nobj[tid] = (b < B) ? nobjs[b] : 0;
    }
    if (tid == 0) s_npos = 0;
    __syncthreads();

    const float a00 = anchors[0], a01 = anchors[1];
    const float a10 = anchors[2], a11 = anchors[3];

    // ---- Phase 1: per-target assignment ----
    for (int j = tid; j < kTgt; j += kBlock) {
        const int bl = j / kM;
        const int m  = j - bl * kM;
        short cell = -1;
        float4 tv = make_float4(0.f, 0.f, 0.f, 0.f);
        if (b0 + bl < B) {
            const float4 box = ((const float4*)tboxes)[(size_t)b0 * kM + j];
            const float x1 = box.x, y1 = box.y, x2 = box.z, y2 = box.w;
            const float cx = (x1 + x2) * 0.5f, cy = (y1 + y2) * 0.5f;
            const float w = x2 - x1, h = y2 - y1;
            if (w > 0.f && h > 0.f && m < s_nobj[bl]) {
                const int gi = min(max((int)floorf(cy * (float)kG), 0), kG - 1);
                const int gj = min(max((int)floorf(cx * (float)kG), 0), kG - 1);
                const float wg = w * (float)kG, hg = h * (float)kG;
                const float i0 = fminf(wg, a00) * fminf(hg, a01);
                const float u0 = wg * hg + a00 * a01 - i0;
                const float r0 = i0 / (u0 + 1e-6f);
                const float i1 = fminf(wg, a10) * fminf(hg, a11);
                const float u1 = wg * hg + a10 * a11 - i1;
                const float r1 = i1 / (u1 + 1e-6f);
                const int a = (r1 > r0) ? 1 : 0;   // argmax, first-max wins
                const float aw = a ? a10 : a00;
                const float ah = a ? a11 : a01;
                tv.x = cx * (float)kG - (float)gj;
                tv.y = cy * (float)kG - (float)gi;
                tv.z = __logf(fmaxf(wg, 0.01f) / (aw + 1e-6f));
                tv.w = __logf(fmaxf(hg, 0.01f) / (ah + 1e-6f));
                cell = (short)(bl * kCells + (gi * kG + gj) * kA + a);
            }
        }
        s_cell[j] = cell;
        s_tv[j] = tv;
    }
    __syncthreads();

    // ---- Phase 1b: dedup (last-write-wins) + compaction ----
    for (int j = tid; j < kTgt; j += kBlock) {
        const short c = s_cell[j];
        if (c >= 0) {
            const int bl = j / kM;
            const int m  = j - bl * kM;
            bool win = true;
            for (int m2 = m + 1; m2 < kM; ++m2) {
                if (s_cell[bl * kM + m2] == c) { win = false; break; }
            }
            if (win) {
                const int idx = atomicAdd(&s_npos, 1);
                s_pos[idx] = (j << 16) | (int)c;
            }
        }
    }
    __syncthreads();

    // ---- Phase 2: branchless stream of all obj logits ----
    float accO = 0.f, accN = 0.f, accB = 0.f, accC = 0.f;
    const float* __restrict__ pblk = preds + (size_t)b0 * kCells * kCh;
    if (b0 + kNB <= B) {
        #pragma unroll
        for (int k = 0; k < kIters; ++k) {
            const float po = pblk[(size_t)(tid + k * kBlock) * kCh];
            accN += softplus_fast(po);
        }
    } else {
        const int ncell = (B - b0) * kCells;
        for (int i = tid; i < ncell; i += kBlock)
            accN += softplus_fast(pblk[(size_t)i * kCh]);
    }

    // ---- Phase 2b: compacted positives ----
    const int np = s_npos;
    const float cw0 = cweights[0], cw1 = cweights[1], cw2 = cweights[2];
    for (int t = tid; t < np; t += kBlock) {
        const int pk = s_pos[t];
        const int j  = pk >> 16;
        const int ci = pk & 0xFFFF;
        const float4* pc = (const float4*)(pblk + (size_t)ci * kCh);
        const float4 p0 = pc[0];
        const float4 p1 = pc[1];
        const float spp = softplus_fast(p0.x);
        accN -= spp;            // remove wrongly-added noobj term
        accO += spp - p0.x;     // softplus(-x) == softplus(x) - x
        const float4 tv = s_tv[j];
        float d, ad;
        d = p0.y - tv.x; ad = fabsf(d); accB += (ad < 1.f) ? 0.5f * d * d : ad - 0.5f;
        d = p0.z - tv.y; ad = fabsf(d); accB += (ad < 1.f) ? 0.5f * d * d : ad - 0.5f;
        d = p0.w - tv.z; ad = fabsf(d); accB += (ad < 1.f) ? 0.5f * d * d : ad - 0.5f;
        d = p1.x - tv.w; ad = fabsf(d); accB += (ad < 1.f) ? 0.5f * d * d : ad - 0.5f;
        const int lab = tlabels[(size_t)b0 * kM + j];
        const float c0 = p1.y, c1 = p1.z, c2 = p1.w;
        const float mx = fmaxf(c0, fmaxf(c1, c2));
        const float lse = mx + __logf(__expf(c0 - mx) + __expf(c1 - mx) + __expf(c2 - mx));
        const float logit = (lab == 0) ? c0 : ((lab == 1) ? c1 : c2);
        const float cwv   = (lab == 0) ? cw0 : ((lab == 1) ? cw1 : cw2);
        accC += cwv * (lse - logit);
    }

    // ---- Block reduce (4 float sums) + plain SoA stores ----
    float vals[4] = {accO, accN, accB, accC};
    #pragma unroll
    for (int k = 0; k < 4; ++k) {
        float v = vals[k];
        #pragma unroll
        for (int off = 32; off > 0; off >>= 1) v += __shfl_down(v, off, 64);
        vals[k] = v;
    }
    const int wave = tid >> 6;
    const int lane = tid & 63;
    if (lane == 0) {
        #pragma unroll
        for (int k = 0; k < 4; ++k) s_red[wave][k] = vals[k];
    }
    __syncthreads();
    if (tid == 0) {
        const int nb = gridDim.x;
        #pragma unroll
        for (int k = 0; k < 4; ++k) {
            float t = 0.f;
            #pragma unroll
            for (int w = 0; w < kBlock / 64; ++w) t += s_red[w][k];
            partial[(size_t)k * nb + blockIdx.x] = t;
        }
        partial[(size_t)4 * nb + blockIdx.x] = (float)np;   // num_pos
    }
}

__global__ __launch_bounds__(256) void det_loss_reduce(
    const float* __restrict__ partial, int nblocks, float* __restrict__ out)
{
    __shared__ float s_red[4][5];
    const int tid = threadIdx.x;
    float v[5] = {0.f, 0.f, 0.f, 0.f, 0.f};
    for (int i = tid; i < nblocks; i += 256) {
        #pragma unroll
        for (int k = 0; k < 5; ++k) v[k] += partial[(size_t)k * nblocks + i];
    }
    #pragma unroll
    for (int k = 0; k < 5; ++k) {
        float x = v[k];
        #pragma unroll
        for (int off = 32; off > 0; off >>= 1) x += __shfl_down(x, off, 64);
        v[k] = x;
    }
    const int wave = tid >> 6;
    const int lane = tid & 63;
    if (lane == 0) {
        #pragma unroll
        for (int k = 0; k < 5; ++k) s_red[wave][k] = v[k];
    }
    __syncthreads();
    if (tid == 0) {
        float t[5];
        #pragma unroll
        for (int k = 0; k < 5; ++k) {
            float s = 0.f;
            #pragma unroll
            for (int w = 0; w < 4; ++w) s += s_red[w][k];
            t[k] = s;
        }
        const float npv = fmaxf(t[4], 1.0f);
        out[0] = (5.0f * t[2] + 1.0f * t[0] + 0.5f * t[1] + 2.0f * t[3]) / npv;
    }
}

extern "C" void kernel_launch(void* const* d_in, const int* in_sizes, int n_in,
                              void* d_out, int out_size, void* d_ws, size_t ws_size,
                              hipStream_t stream) {
    const float* preds    = (const float*)d_in[0];
    const float* tboxes   = (const float*)d_in[1];
    const int*   tlabels  = (const int*)d_in[2];
    const int*   nobjs    = (const int*)d_in[3];
    const float* anchors  = (const float*)d_in[4];
    const float* cweights = (const float*)d_in[5];
    float* out = (float*)d_out;
    float* partial = (float*)d_ws;   // [5][nblocks], fully overwritten every call

    const int B = in_sizes[0] / (kCells * kCh);   // /784
    const int blocks = (B + kNB - 1) / kNB;

    det_loss_main<<<blocks, kBlock, 0, stream>>>(
        preds, tboxes, tlabels, nobjs, anchors, cweights, partial, B);
    det_loss_reduce<<<1, 256, 0, stream>>>(partial, blocks, out);
}